// Round 23
// baseline (431.468 us; speedup 1.0000x reference)
//
#include <hip/hip_runtime.h>

#define Bb 64
#define Tt 256
#define Cc 384
#define Ll 3
#define Hh 6
#define HD 64
#define Vv 65
#define FF 1536
#define NT (Bb*Tt)        // 16384 tokens
#define CQ 1152           // fused qkv width
#define LDP 72            // attn LDS row stride (u16)

typedef unsigned short u16;
typedef unsigned int   u32;
typedef __attribute__((ext_vector_type(8))) short bf16x8;
typedef __attribute__((ext_vector_type(4))) float f32x4;

__device__ __forceinline__ float bf2f(u16 u) {
    u32 v = ((u32)u) << 16; float f; __builtin_memcpy(&f, &v, 4); return f;
}
__device__ __forceinline__ u16 f2bf(float f) {
    u32 u; __builtin_memcpy(&u, &f, 4);
    u = (u + 0x7fffu + ((u >> 16) & 1u)) >> 16;
    return (u16)u;
}
__device__ __forceinline__ void gload16(const void* g, void* l) {
    __builtin_amdgcn_global_load_lds(
        (const __attribute__((address_space(1))) u32*)g,
        (__attribute__((address_space(3))) u32*)l, 16, 0, 0);
}

// ---------------- fused embed + LN(layer0): one wave per token, float2-vectorized ----------------
__global__ __launch_bounds__(256) void k_embed_ln(const int* __restrict__ idx,
    const float* __restrict__ tok, const float* __restrict__ pos,
    const float* __restrict__ g, const float* __restrict__ b,
    float* __restrict__ x, u16* __restrict__ h)
{
    int bt   = (int)((blockIdx.x * 256 + threadIdx.x) >> 6);
    int lane = threadIdx.x & 63;
    int t = bt % Tt;
    const float2* tr = (const float2*)(tok + (long)idx[bt] * Cc);
    const float2* pr = (const float2*)(pos + (long)t * Cc);
    float2 v[3]; float s = 0.f;
    #pragma unroll
    for (int j = 0; j < 3; ++j) {
        int c = lane + 64 * j;
        float2 tv = tr[c], pv = pr[c];
        v[j].x = tv.x + pv.x; v[j].y = tv.y + pv.y;
        s += v[j].x + v[j].y;
    }
    float2* xr = (float2*)(x + (long)bt * Cc);
    #pragma unroll
    for (int j = 0; j < 3; ++j) xr[lane + 64 * j] = v[j];
    #pragma unroll
    for (int m = 32; m; m >>= 1) s += __shfl_xor(s, m, 64);
    float mean = s * (1.f / 384.f);
    float q = 0.f;
    #pragma unroll
    for (int j = 0; j < 3; ++j) {
        float dx = v[j].x - mean, dy = v[j].y - mean;
        q += dx * dx + dy * dy;
    }
    #pragma unroll
    for (int m = 32; m; m >>= 1) q += __shfl_xor(q, m, 64);
    float rstd = rsqrtf(q * (1.f / 384.f) + 1e-5f);
    u32* hr = (u32*)(h + (long)bt * Cc);
    const float2* gr = (const float2*)g;
    const float2* br = (const float2*)b;
    #pragma unroll
    for (int j = 0; j < 3; ++j) {
        int c = lane + 64 * j;
        float2 gv = gr[c], bv = br[c];
        u32 lo = f2bf((v[j].x - mean) * rstd * gv.x + bv.x);
        u32 hi = f2bf((v[j].y - mean) * rstd * gv.y + bv.y);
        hr[c] = lo | (hi << 16);
    }
}

// ---------------- layernorm: fp32 in -> bf16 out, one wave per row, float2-vectorized ----------------
__global__ __launch_bounds__(256) void k_ln(const float* __restrict__ x,
    const float* __restrict__ g, const float* __restrict__ b, u16* __restrict__ h)
{
    int row  = (int)((blockIdx.x * 256 + threadIdx.x) >> 6);
    int lane = threadIdx.x & 63;
    const float2* xr = (const float2*)(x + (long)row * Cc);
    float2 v[3]; float s = 0.f;
    #pragma unroll
    for (int j = 0; j < 3; ++j) { v[j] = xr[lane + 64 * j]; s += v[j].x + v[j].y; }
    #pragma unroll
    for (int m = 32; m; m >>= 1) s += __shfl_xor(s, m, 64);
    float mean = s * (1.f / 384.f);
    float q = 0.f;
    #pragma unroll
    for (int j = 0; j < 3; ++j) {
        float dx = v[j].x - mean, dy = v[j].y - mean;
        q += dx * dx + dy * dy;
    }
    #pragma unroll
    for (int m = 32; m; m >>= 1) q += __shfl_xor(q, m, 64);
    float rstd = rsqrtf(q * (1.f / 384.f) + 1e-5f);
    u32* hr = (u32*)(h + (long)row * Cc);
    const float2* gr = (const float2*)g;
    const float2* br = (const float2*)b;
    #pragma unroll
    for (int j = 0; j < 3; ++j) {
        int c = lane + 64 * j;
        float2 gv = gr[c], bv = br[c];
        u32 lo = f2bf((v[j].x - mean) * rstd * gv.x + bv.x);
        u32 hi = f2bf((v[j].y - mean) * rstd * gv.y + bv.y);
        hr[c] = lo | (hi << 16);
    }
}

// ---------------- fused weight convert+transpose (all 18 big matrices) ----------------
__global__ __launch_bounds__(256) void k_cvtT_all(
    const float* __restrict__ Wq, const float* __restrict__ Wk,
    const float* __restrict__ Wv, const float* __restrict__ Wo,
    const float* __restrict__ W1, const float* __restrict__ W2,
    u16* __restrict__ Wqkvt, u16* __restrict__ Wot,
    u16* __restrict__ W1t, u16* __restrict__ W2t)
{
    int t = blockIdx.x;
    const float* src; u16* dst; int K, N, tt;
    if (t < 1728) {
        int m = t / 144; tt = t % 144; K = Cc; N = Cc;
        if (m < 9) {
            int l = m / 3, q = m % 3;
            src = (q == 0 ? Wq : q == 1 ? Wk : Wv) + (size_t)l * Cc * Cc;
            dst = Wqkvt + (size_t)l * CQ * Cc + (size_t)q * Cc * Cc;
        } else {
            int l = m - 9;
            src = Wo + (size_t)l * Cc * Cc;
            dst = Wot + (size_t)l * Cc * Cc;
        }
    } else if (t < 3456) {
        int u = t - 1728; int l = u / 576; tt = u % 576; K = Cc; N = FF;
        src = W1 + (size_t)l * Cc * FF; dst = W1t + (size_t)l * FF * Cc;
    } else {
        int u = t - 3456; int l = u / 576; tt = u % 576; K = FF; N = Cc;
        src = W2 + (size_t)l * FF * Cc; dst = W2t + (size_t)l * Cc * FF;
    }
    int nk = K / 32;
    int kt = (tt % nk) * 32, nt = (tt / nk) * 32;
    __shared__ u16 tile[32][33];
    int tx = threadIdx.x & 31, ty = threadIdx.x >> 5;
    #pragma unroll
    for (int r = 0; r < 4; ++r)
        tile[ty + 8 * r][tx] = f2bf(src[(long)(kt + ty + 8 * r) * N + nt + tx]);
    __syncthreads();
    #pragma unroll
    for (int r = 0; r < 4; ++r)
        dst[(long)(nt + ty + 8 * r) * K + kt + tx] = tile[tx][ty + 8 * r];
}

// Wlm: [384][65] f32 -> padded [128][384] bf16
__global__ void k_cvtT_lm(const float* __restrict__ W, u16* __restrict__ Wt)
{
    int i = blockIdx.x * 256 + threadIdx.x;
    if (i >= 128 * Cc) return;
    int k = i % Cc, n = i / Cc;
    Wt[i] = (n < Vv) ? f2bf(W[(long)k * Vv + n]) : (u16)0;
}

// ---------------- 128x128 MFMA GEMM, BK=64, A single + B double (validated r19) ----------------
// EPI 0: ->bf16 (no bias); EPI 1: +bias, relu -> bf16
template<int EPI>
__global__ __launch_bounds__(256) void k_gemm128(
    const u16* __restrict__ A, const u16* __restrict__ Bt,
    const float* __restrict__ bias, void* __restrict__ Cout, int M, int N, int K)
{
    __shared__ __align__(16) u16 As[128 * 64];      // 16 KB (single)
    __shared__ __align__(16) u16 Bs[2][128 * 64];   // 32 KB (double)
    const int bm = blockIdx.x * 128;
    const int bn = blockIdx.y * 128;
    const int tid = threadIdx.x;
    const int lane = tid & 63, w = tid >> 6;
    const int wr = w >> 1, wc = w & 1;
    const int l15 = lane & 15, g = lane >> 4;
    const int lr = lane >> 3;
    const int lc = ((lane & 7) ^ lr) * 8;      // pre-swizzled source column

    f32x4 acc[4][4] = {};
    const u16* Ag = A  + (long)(bm + w * 32 + lr) * K + lc;
    const u16* Bg = Bt + (long)(bn + w * 32 + lr) * K + lc;

    auto stageA = [&](int k0) {
        u16* Ad = As + (w * 4) * 512;
        #pragma unroll
        for (int s = 0; s < 4; ++s)
            gload16(Ag + (long)s * 8 * K + k0, Ad + s * 512);
    };
    auto stageB = [&](int buf, int k0) {
        u16* Bd = Bs[buf] + (w * 4) * 512;
        #pragma unroll
        for (int s = 0; s < 4; ++s)
            gload16(Bg + (long)s * 8 * K + k0, Bd + s * 512);
    };
    const int nt = K / 64;
    stageB(0, 0);
    stageA(0);
    if (nt > 1) stageB(1, 64);
    for (int t = 0; t < nt; ++t) {
        if (t < nt - 1) asm volatile("s_waitcnt vmcnt(4)" ::: "memory");
        else            asm volatile("s_waitcnt vmcnt(0)" ::: "memory");
        __builtin_amdgcn_s_barrier();
        asm volatile("" ::: "memory");
        const char* Abuf = (const char*)As;
        const char* Bbuf = (const char*)Bs[t & 1];
        #pragma unroll
        for (int hh = 0; hh < 2; ++hh) {
            const int cs = hh * 4 + g;
            bf16x8 af[4], bfr[4];
            #pragma unroll
            for (int mi = 0; mi < 4; ++mi) {
                int row = wr * 64 + mi * 16 + l15;
                af[mi] = *(const bf16x8*)(Abuf + row * 128 + ((cs ^ (row & 7)) << 4));
            }
            #pragma unroll
            for (int ni = 0; ni < 4; ++ni) {
                int row = wc * 64 + ni * 16 + l15;
                bfr[ni] = *(const bf16x8*)(Bbuf + row * 128 + ((cs ^ (row & 7)) << 4));
            }
            #pragma unroll
            for (int mi = 0; mi < 4; ++mi)
            #pragma unroll
            for (int ni = 0; ni < 4; ++ni)
                acc[mi][ni] = __builtin_amdgcn_mfma_f32_16x16x32_bf16(af[mi], bfr[ni], acc[mi][ni], 0, 0, 0);
        }
        asm volatile("" ::: "memory");
        __builtin_amdgcn_s_barrier();
        if (t + 1 < nt) stageA((t + 1) * 64);
        if (t + 2 < nt) stageB(t & 1, (t + 2) * 64);
    }
    #pragma unroll
    for (int mi = 0; mi < 4; ++mi)
    #pragma unroll
    for (int ni = 0; ni < 4; ++ni)
    #pragma unroll
    for (int i = 0; i < 4; ++i) {
        int row = bm + wr * 64 + mi * 16 + g * 4 + i;
        int col = bn + wc * 64 + ni * 16 + l15;
        float v = acc[mi][ni][i];
        if constexpr (EPI == 1) v = fmaxf(v + bias[col], 0.f);
        ((u16*)Cout)[(long)row * N + col] = f2bf(v);
    }
}

// ---------------- 128x64 MFMA GEMM (narrow N) ----------------
// PIPE 0: single-buffer 24 KB (6 blk/CU) -- Wo (K=384), lm-head
// PIPE 1: A double + B single, 40 KB (4 blk/CU), counted vmcnt -- W2 (K=1536)
// EPI 2: +bias, +R -> f32; EPI 3: +bias, col<Nout -> f32 (stride Nout)
template<int EPI, int PIPE>
__global__ __launch_bounds__(256) void k_gemm_n64(
    const u16* __restrict__ A, const u16* __restrict__ Bt,
    const float* __restrict__ bias, const float* __restrict__ R,
    void* __restrict__ Cout, int M, int N, int K, int Nout)
{
    __shared__ __align__(16) u16 As[PIPE ? 2 : 1][128 * 64];
    __shared__ __align__(16) u16 Bs[64 * 64];
    const int bm = blockIdx.x * 128;
    const int bn = blockIdx.y * 64;
    const int tid = threadIdx.x;
    const int lane = tid & 63, w = tid >> 6;
    const int l15 = lane & 15, g = lane >> 4;
    const int lr = lane >> 3;
    const int lc = ((lane & 7) ^ lr) * 8;

    f32x4 acc[2][4] = {};
    const u16* Ag = A  + (long)(bm + w * 32 + lr) * K + lc;
    const u16* Bg = Bt + (long)(bn + w * 16 + lr) * K + lc;

    auto stageA = [&](int buf, int k0) {
        u16* Ad = As[buf] + (w * 4) * 512;
        #pragma unroll
        for (int s = 0; s < 4; ++s)
            gload16(Ag + (long)s * 8 * K + k0, Ad + s * 512);
    };
    auto stageB = [&](int k0) {
        u16* Bd = Bs + (w * 2) * 512;
        #pragma unroll
        for (int t = 0; t < 2; ++t)
            gload16(Bg + (long)t * 8 * K + k0, Bd + t * 512);
    };
    auto compute = [&](const char* Abuf) {
        const char* Bbuf = (const char*)Bs;
        #pragma unroll
        for (int hh = 0; hh < 2; ++hh) {
            const int cs = hh * 4 + g;
            bf16x8 af[2], bfr[4];
            #pragma unroll
            for (int mi = 0; mi < 2; ++mi) {
                int row = w * 32 + mi * 16 + l15;
                af[mi] = *(const bf16x8*)(Abuf + row * 128 + ((cs ^ (row & 7)) << 4));
            }
            #pragma unroll
            for (int ni = 0; ni < 4; ++ni) {
                int row = ni * 16 + l15;
                bfr[ni] = *(const bf16x8*)(Bbuf + row * 128 + ((cs ^ (row & 7)) << 4));
            }
            #pragma unroll
            for (int mi = 0; mi < 2; ++mi)
            #pragma unroll
            for (int ni = 0; ni < 4; ++ni)
                acc[mi][ni] = __builtin_amdgcn_mfma_f32_16x16x32_bf16(af[mi], bfr[ni], acc[mi][ni], 0, 0, 0);
        }
    };

    if constexpr (PIPE == 0) {
        for (int k0 = 0; k0 < K; k0 += 64) {
            stageA(0, k0);
            stageB(k0);
            __syncthreads();
            compute((const char*)As[0]);
            __syncthreads();
        }
    } else {
        const int nt = K / 64;
        stageA(0, 0);
        stageB(0);
        if (nt > 1) stageA(1, 64);
        for (int t = 0; t < nt; ++t) {
            if (t < nt - 1) asm volatile("s_waitcnt vmcnt(4)" ::: "memory");
            else            asm volatile("s_waitcnt vmcnt(0)" ::: "memory");
            __builtin_amdgcn_s_barrier();
            asm volatile("" ::: "memory");
            compute((const char*)As[t & 1]);
            asm volatile("" ::: "memory");
            __builtin_amdgcn_s_barrier();
            if (t + 1 < nt) stageB((t + 1) * 64);
            if (t + 2 < nt) stageA(t & 1, (t + 2) * 64);
        }
    }
    #pragma unroll
    for (int mi = 0; mi < 2; ++mi)
    #pragma unroll
    for (int ni = 0; ni < 4; ++ni)
    #pragma unroll
    for (int i = 0; i < 4; ++i) {
        int row = bm + w * 32 + mi * 16 + g * 4 + i;
        int col = bn + ni * 16 + l15;
        float v = acc[mi][ni][i];
        if constexpr (EPI == 2) {
            long o = (long)row * N + col;
            ((float*)Cout)[o] = v + bias[col] + R[o];
        } else {
            if (col < Nout)
                ((float*)Cout)[(long)row * Nout + col] = v + bias[col];
        }
    }
}

// ---------------- MFMA flash attention (validated; qkv stride CQ) ----------------
__global__ __launch_bounds__(256) void k_attn_mfma(const u16* __restrict__ qkv,
                                                   u16* __restrict__ att)
{
    __shared__ __align__(16) u16 ks[64][LDP];
    __shared__ __align__(16) u16 vt[64][LDP];
    __shared__ __align__(16) u16 pt[4][16][LDP];
    const int qt = blockIdx.x, hh = blockIdx.y, b = blockIdx.z;
    const int tid = threadIdx.x, lane = tid & 63, w = tid >> 6;
    const int l15 = lane & 15, g = lane >> 4;
    const int q0 = qt * 64;
    const long tokbase = (long)b * Tt;
    const float scale = 0.051031036307982884f;

    bf16x8 qa0, qa1;
    {
        const u16* qp = qkv + (tokbase + q0 + w * 16 + l15) * CQ + hh * HD + g * 8;
        qa0 = *(const bf16x8*)(qp);
        qa1 = *(const bf16x8*)(qp + 32);
    }
    f32x4 o[4] = {};
    float mrow[4] = {-1e30f, -1e30f, -1e30f, -1e30f};
    float lrow[4] = {0.f, 0.f, 0.f, 0.f};

    for (int kt = 0; kt <= qt; ++kt) {
        {
            int key = tid >> 2, c0 = (tid & 3) * 16;
            const u16* kg = qkv + (tokbase + kt * 64 + key) * CQ + Cc     + hh * HD + c0;
            const u16* vg = qkv + (tokbase + kt * 64 + key) * CQ + 2 * Cc + hh * HD + c0;
            *(bf16x8*)&ks[key][c0]     = *(const bf16x8*)kg;
            *(bf16x8*)&ks[key][c0 + 8] = *(const bf16x8*)(kg + 8);
            bf16x8 v0 = *(const bf16x8*)vg;
            bf16x8 v1 = *(const bf16x8*)(vg + 8);
            #pragma unroll
            for (int j = 0; j < 8; ++j) vt[c0 + j][key]     = (u16)v0[j];
            #pragma unroll
            for (int j = 0; j < 8; ++j) vt[c0 + 8 + j][key] = (u16)v1[j];
        }
        __syncthreads();
        f32x4 s[4] = {};
        #pragma unroll
        for (int c = 0; c < 4; ++c) {
            bf16x8 kb0 = *(const bf16x8*)&ks[c * 16 + l15][g * 8];
            bf16x8 kb1 = *(const bf16x8*)&ks[c * 16 + l15][32 + g * 8];
            s[c] = __builtin_amdgcn_mfma_f32_16x16x32_bf16(qa0, kb0, s[c], 0, 0, 0);
            s[c] = __builtin_amdgcn_mfma_f32_16x16x32_bf16(qa1, kb1, s[c], 0, 0, 0);
        }
        const bool diag = (kt == qt);
        #pragma unroll
        for (int c = 0; c < 4; ++c)
        #pragma unroll
        for (int i = 0; i < 4; ++i) {
            float v = s[c][i] * scale;
            if (diag && (c * 16 + l15 > w * 16 + 4 * g + i)) v = -1e30f;
            s[c][i] = v;
        }
        #pragma unroll
        for (int i = 0; i < 4; ++i) {
            float m0 = fmaxf(fmaxf(s[0][i], s[1][i]), fmaxf(s[2][i], s[3][i]));
            #pragma unroll
            for (int mm = 1; mm < 16; mm <<= 1) m0 = fmaxf(m0, __shfl_xor(m0, mm, 64));
            float mn = fmaxf(mrow[i], m0);
            float alpha = __expf(mrow[i] - mn);
            mrow[i] = mn;
            float sum = 0.f;
            #pragma unroll
            for (int c = 0; c < 4; ++c) {
                float p = __expf(s[c][i] - mn);
                s[c][i] = p;
                sum += p;
            }
            #pragma unroll
            for (int mm = 1; mm < 16; mm <<= 1) sum += __shfl_xor(sum, mm, 64);
            lrow[i] = lrow[i] * alpha + sum;
            #pragma unroll
            for (int d = 0; d < 4; ++d) o[d][i] *= alpha;
        }
        #pragma unroll
        for (int c = 0; c < 4; ++c)
        #pragma unroll
        for (int i = 0; i < 4; ++i)
            pt[w][g * 4 + i][c * 16 + l15] = f2bf(s[c][i]);
        bf16x8 pa0 = *(const bf16x8*)&pt[w][l15][g * 8];
        bf16x8 pa1 = *(const bf16x8*)&pt[w][l15][32 + g * 8];
        #pragma unroll
        for (int d = 0; d < 4; ++d) {
            bf16x8 vb0 = *(const bf16x8*)&vt[d * 16 + l15][g * 8];
            bf16x8 vb1 = *(const bf16x8*)&vt[d * 16 + l15][32 + g * 8];
            o[d] = __builtin_amdgcn_mfma_f32_16x16x32_bf16(pa0, vb0, o[d], 0, 0, 0);
            o[d] = __builtin_amdgcn_mfma_f32_16x16x32_bf16(pa1, vb1, o[d], 0, 0, 0);
        }
        __syncthreads();
    }
    #pragma unroll
    for (int i = 0; i < 4; ++i) {
        float inv = 1.f / lrow[i];
        int row = q0 + w * 16 + g * 4 + i;
        u16* ap = att + (tokbase + row) * Cc + hh * HD;
        #pragma unroll
        for (int d = 0; d < 4; ++d)
            ap[d * 16 + l15] = f2bf(o[d][i] * inv);
    }
}

extern "C" void kernel_launch(void* const* d_in, const int* in_sizes, int n_in,
                              void* d_out, int out_size, void* d_ws, size_t ws_size,
                              hipStream_t stream)
{
    (void)in_sizes; (void)n_in; (void)out_size; (void)ws_size;
    const int*   idx  = (const int*)d_in[0];
    const float* tok  = (const float*)d_in[1];
    const float* pos  = (const float*)d_in[2];
    const float* Wq   = (const float*)d_in[3];
    const float* Wk   = (const float*)d_in[4];
    const float* Wv   = (const float*)d_in[5];
    const float* Wo   = (const float*)d_in[6];
    const float* bo   = (const float*)d_in[7];
    const float* ln1g = (const float*)d_in[8];
    const float* ln1b = (const float*)d_in[9];
    const float* ln2g = (const float*)d_in[10];
    const float* ln2b = (const float*)d_in[11];
    const float* W1   = (const float*)d_in[12];
    const float* b1   = (const float*)d_in[13];
    const float* W2   = (const float*)d_in[14];
    const float* b2   = (const float*)d_in[15];
    const float* lnfg = (const float*)d_in[16];
    const float* lnfb = (const float*)d_in[17];
    const float* Wlm  = (const float*)d_in[18];
    const float* blm  = (const float*)d_in[19];

    char* w = (char*)d_ws;
    auto carve = [&](size_t bytes) { char* p = w; w += (bytes + 255) & ~(size_t)255; return p; };
    float* x   = (float*)carve((size_t)NT * Cc * 4);
    u16*  big  = (u16*)carve((size_t)NT * FF * 2);   // fb (NT*FF) and qkvb (NT*CQ) share
    u16*  h    = (u16*)carve((size_t)NT * Cc * 2);
    u16*  ab   = (u16*)carve((size_t)NT * Cc * 2);
    u16*  Wqkvt= (u16*)carve((size_t)Ll * CQ * Cc * 2);
    u16*  Wot  = (u16*)carve((size_t)Ll * Cc * Cc * 2);
    u16*  W1t  = (u16*)carve((size_t)Ll * FF * Cc * 2);
    u16*  W2t  = (u16*)carve((size_t)Ll * Cc * FF * 2);
    u16*  Wlmt = (u16*)carve((size_t)128 * Cc * 2);
    u16*  qkvb = big;
    u16*  fb   = big;

    const int TPB = 256;
    k_cvtT_all<<<5184, TPB, 0, stream>>>(Wq, Wk, Wv, Wo, W1, W2, Wqkvt, Wot, W1t, W2t);
    k_cvtT_lm<<<(128 * Cc + 255) / 256, TPB, 0, stream>>>(Wlm, Wlmt);
    k_embed_ln<<<NT / 4, TPB, 0, stream>>>(idx, tok, pos, ln1g, ln1b, x, h);

    for (int l = 0; l < Ll; ++l) {
        if (l > 0)
            k_ln<<<NT / 4, TPB, 0, stream>>>(x, ln1g + l * Cc, ln1b + l * Cc, h);
        k_gemm128<0><<<dim3(NT / 128, CQ / 128), TPB, 0, stream>>>(
            h, Wqkvt + (size_t)l * CQ * Cc, nullptr, qkvb, NT, CQ, Cc);
        k_attn_mfma<<<dim3(4, Hh, Bb), TPB, 0, stream>>>(qkvb, ab);
        k_gemm_n64<2, 0><<<dim3(NT / 128, Cc / 64), TPB, 0, stream>>>(
            ab, Wot + (size_t)l * Cc * Cc, bo + l * Cc, x, x, NT, Cc, Cc, Cc);
        k_ln<<<NT / 4, TPB, 0, stream>>>(x, ln2g + l * Cc, ln2b + l * Cc, h);
        k_gemm128<1><<<dim3(NT / 128, FF / 128), TPB, 0, stream>>>(
            h, W1t + (size_t)l * FF * Cc, b1 + l * FF, fb, NT, FF, Cc);
        k_gemm_n64<2, 1><<<dim3(NT / 128, Cc / 64), TPB, 0, stream>>>(
            fb, W2t + (size_t)l * Cc * FF, b2 + l * Cc, x, x, NT, Cc, FF, Cc);
    }
    k_ln<<<NT / 4, TPB, 0, stream>>>(x, lnfg, lnfb, h);
    k_gemm_n64<3, 0><<<dim3(NT / 128, 2), TPB, 0, stream>>>(
        h, Wlmt, blm, nullptr, (float*)d_out, NT, 128, Cc, Vv);
}

// Round 24
// 427.025 us; speedup vs baseline: 1.0104x; 1.0104x over previous
//
#include <hip/hip_runtime.h>

#define Bb 64
#define Tt 256
#define Cc 384
#define Ll 3
#define Hh 6
#define HD 64
#define Vv 65
#define FF 1536
#define NT (Bb*Tt)        // 16384 tokens
#define CQ 1152           // fused qkv width
#define LDP 72            // attn LDS row stride (u16)

typedef unsigned short u16;
typedef unsigned int   u32;
typedef __attribute__((ext_vector_type(8))) short bf16x8;
typedef __attribute__((ext_vector_type(4))) float f32x4;

__device__ __forceinline__ float bf2f(u16 u) {
    u32 v = ((u32)u) << 16; float f; __builtin_memcpy(&f, &v, 4); return f;
}
__device__ __forceinline__ u16 f2bf(float f) {
    u32 u; __builtin_memcpy(&u, &f, 4);
    u = (u + 0x7fffu + ((u >> 16) & 1u)) >> 16;
    return (u16)u;
}
__device__ __forceinline__ void gload16(const void* g, void* l) {
    __builtin_amdgcn_global_load_lds(
        (const __attribute__((address_space(1))) u32*)g,
        (__attribute__((address_space(3))) u32*)l, 16, 0, 0);
}

// ---------------- fused embed + LN(layer0): one wave per token, float2-vectorized ----------------
__global__ __launch_bounds__(256) void k_embed_ln(const int* __restrict__ idx,
    const float* __restrict__ tok, const float* __restrict__ pos,
    const float* __restrict__ g, const float* __restrict__ b,
    float* __restrict__ x, u16* __restrict__ h)
{
    int bt   = (int)((blockIdx.x * 256 + threadIdx.x) >> 6);
    int lane = threadIdx.x & 63;
    int t = bt % Tt;
    const float2* tr = (const float2*)(tok + (long)idx[bt] * Cc);
    const float2* pr = (const float2*)(pos + (long)t * Cc);
    float2 v[3]; float s = 0.f;
    #pragma unroll
    for (int j = 0; j < 3; ++j) {
        int c = lane + 64 * j;
        float2 tv = tr[c], pv = pr[c];
        v[j].x = tv.x + pv.x; v[j].y = tv.y + pv.y;
        s += v[j].x + v[j].y;
    }
    float2* xr = (float2*)(x + (long)bt * Cc);
    #pragma unroll
    for (int j = 0; j < 3; ++j) xr[lane + 64 * j] = v[j];
    #pragma unroll
    for (int m = 32; m; m >>= 1) s += __shfl_xor(s, m, 64);
    float mean = s * (1.f / 384.f);
    float q = 0.f;
    #pragma unroll
    for (int j = 0; j < 3; ++j) {
        float dx = v[j].x - mean, dy = v[j].y - mean;
        q += dx * dx + dy * dy;
    }
    #pragma unroll
    for (int m = 32; m; m >>= 1) q += __shfl_xor(q, m, 64);
    float rstd = rsqrtf(q * (1.f / 384.f) + 1e-5f);
    u32* hr = (u32*)(h + (long)bt * Cc);
    const float2* gr = (const float2*)g;
    const float2* br = (const float2*)b;
    #pragma unroll
    for (int j = 0; j < 3; ++j) {
        int c = lane + 64 * j;
        float2 gv = gr[c], bv = br[c];
        u32 lo = f2bf((v[j].x - mean) * rstd * gv.x + bv.x);
        u32 hi = f2bf((v[j].y - mean) * rstd * gv.y + bv.y);
        hr[c] = lo | (hi << 16);
    }
}

// ---------------- layernorm: fp32 in -> bf16 out, one wave per row, float2-vectorized ----------------
__global__ __launch_bounds__(256) void k_ln(const float* __restrict__ x,
    const float* __restrict__ g, const float* __restrict__ b, u16* __restrict__ h)
{
    int row  = (int)((blockIdx.x * 256 + threadIdx.x) >> 6);
    int lane = threadIdx.x & 63;
    const float2* xr = (const float2*)(x + (long)row * Cc);
    float2 v[3]; float s = 0.f;
    #pragma unroll
    for (int j = 0; j < 3; ++j) { v[j] = xr[lane + 64 * j]; s += v[j].x + v[j].y; }
    #pragma unroll
    for (int m = 32; m; m >>= 1) s += __shfl_xor(s, m, 64);
    float mean = s * (1.f / 384.f);
    float q = 0.f;
    #pragma unroll
    for (int j = 0; j < 3; ++j) {
        float dx = v[j].x - mean, dy = v[j].y - mean;
        q += dx * dx + dy * dy;
    }
    #pragma unroll
    for (int m = 32; m; m >>= 1) q += __shfl_xor(q, m, 64);
    float rstd = rsqrtf(q * (1.f / 384.f) + 1e-5f);
    u32* hr = (u32*)(h + (long)row * Cc);
    const float2* gr = (const float2*)g;
    const float2* br = (const float2*)b;
    #pragma unroll
    for (int j = 0; j < 3; ++j) {
        int c = lane + 64 * j;
        float2 gv = gr[c], bv = br[c];
        u32 lo = f2bf((v[j].x - mean) * rstd * gv.x + bv.x);
        u32 hi = f2bf((v[j].y - mean) * rstd * gv.y + bv.y);
        hr[c] = lo | (hi << 16);
    }
}

// ---------------- fused weight convert+transpose (all 18 big matrices) ----------------
__global__ __launch_bounds__(256) void k_cvtT_all(
    const float* __restrict__ Wq, const float* __restrict__ Wk,
    const float* __restrict__ Wv, const float* __restrict__ Wo,
    const float* __restrict__ W1, const float* __restrict__ W2,
    u16* __restrict__ Wqkvt, u16* __restrict__ Wot,
    u16* __restrict__ W1t, u16* __restrict__ W2t)
{
    int t = blockIdx.x;
    const float* src; u16* dst; int K, N, tt;
    if (t < 1728) {
        int m = t / 144; tt = t % 144; K = Cc; N = Cc;
        if (m < 9) {
            int l = m / 3, q = m % 3;
            src = (q == 0 ? Wq : q == 1 ? Wk : Wv) + (size_t)l * Cc * Cc;
            dst = Wqkvt + (size_t)l * CQ * Cc + (size_t)q * Cc * Cc;
        } else {
            int l = m - 9;
            src = Wo + (size_t)l * Cc * Cc;
            dst = Wot + (size_t)l * Cc * Cc;
        }
    } else if (t < 3456) {
        int u = t - 1728; int l = u / 576; tt = u % 576; K = Cc; N = FF;
        src = W1 + (size_t)l * Cc * FF; dst = W1t + (size_t)l * FF * Cc;
    } else {
        int u = t - 3456; int l = u / 576; tt = u % 576; K = FF; N = Cc;
        src = W2 + (size_t)l * FF * Cc; dst = W2t + (size_t)l * Cc * FF;
    }
    int nk = K / 32;
    int kt = (tt % nk) * 32, nt = (tt / nk) * 32;
    __shared__ u16 tile[32][33];
    int tx = threadIdx.x & 31, ty = threadIdx.x >> 5;
    #pragma unroll
    for (int r = 0; r < 4; ++r)
        tile[ty + 8 * r][tx] = f2bf(src[(long)(kt + ty + 8 * r) * N + nt + tx]);
    __syncthreads();
    #pragma unroll
    for (int r = 0; r < 4; ++r)
        dst[(long)(nt + ty + 8 * r) * K + kt + tx] = tile[tx][ty + 8 * r];
}

// Wlm: [384][65] f32 -> padded [128][384] bf16
__global__ void k_cvtT_lm(const float* __restrict__ W, u16* __restrict__ Wt)
{
    int i = blockIdx.x * 256 + threadIdx.x;
    if (i >= 128 * Cc) return;
    int k = i % Cc, n = i / Cc;
    Wt[i] = (n < Vv) ? f2bf(W[(long)k * Vv + n]) : (u16)0;
}

// ---------------- 128x128 MFMA GEMM, 512 threads (8 waves), A single + B double ----------------
// Wave tile 32x64 (wr=w>>1 rows, wc=w&1 cols). 48 KB LDS -> 3 blk/CU = 6 waves/SIMD.
// r19 hybrid schedule with 2-load stages: prologue B0,A0,B1; iter t waits vmcnt(2)
// (drains B(t)+A(t), keeps B(t+1) in flight); post-barrier stageA(t+1), stageB(t+2).
// EPI 0: ->bf16 (no bias); EPI 1: +bias, relu -> bf16
template<int EPI>
__global__ __launch_bounds__(512, 6) void k_gemm128(
    const u16* __restrict__ A, const u16* __restrict__ Bt,
    const float* __restrict__ bias, void* __restrict__ Cout, int M, int N, int K)
{
    __shared__ __align__(16) u16 As[128 * 64];      // 16 KB (single)
    __shared__ __align__(16) u16 Bs[2][128 * 64];   // 32 KB (double)
    const int bm = blockIdx.x * 128;
    const int bn = blockIdx.y * 128;
    const int tid = threadIdx.x;
    const int lane = tid & 63, w = tid >> 6;       // w = 0..7
    const int wr = w >> 1, wc = w & 1;             // wave tile: rows wr*32, cols wc*64
    const int l15 = lane & 15, g = lane >> 4;
    const int lr = lane >> 3;
    const int lc = ((lane & 7) ^ lr) * 8;          // pre-swizzled source column

    f32x4 acc[2][4] = {};
    // staging: wave w owns segments 2w, 2w+1 (8 rows x 64 cols = 1 KB each)
    const u16* Ag = A  + (long)(bm + w * 16 + lr) * K + lc;
    const u16* Bg = Bt + (long)(bn + w * 16 + lr) * K + lc;

    auto stageA = [&](int k0) {
        u16* Ad = As + (w * 2) * 512;
        #pragma unroll
        for (int s = 0; s < 2; ++s)
            gload16(Ag + (long)s * 8 * K + k0, Ad + s * 512);
    };
    auto stageB = [&](int buf, int k0) {
        u16* Bd = Bs[buf] + (w * 2) * 512;
        #pragma unroll
        for (int s = 0; s < 2; ++s)
            gload16(Bg + (long)s * 8 * K + k0, Bd + s * 512);
    };
    const int nt = K / 64;
    stageB(0, 0);
    stageA(0);
    if (nt > 1) stageB(1, 64);
    for (int t = 0; t < nt; ++t) {
        if (t < nt - 1) asm volatile("s_waitcnt vmcnt(2)" ::: "memory");
        else            asm volatile("s_waitcnt vmcnt(0)" ::: "memory");
        __builtin_amdgcn_s_barrier();
        asm volatile("" ::: "memory");
        const char* Abuf = (const char*)As;
        const char* Bbuf = (const char*)Bs[t & 1];
        #pragma unroll
        for (int hh = 0; hh < 2; ++hh) {
            const int cs = hh * 4 + g;
            bf16x8 af[2], bfr[4];
            #pragma unroll
            for (int mi = 0; mi < 2; ++mi) {
                int row = wr * 32 + mi * 16 + l15;
                af[mi] = *(const bf16x8*)(Abuf + row * 128 + ((cs ^ (row & 7)) << 4));
            }
            #pragma unroll
            for (int ni = 0; ni < 4; ++ni) {
                int row = wc * 64 + ni * 16 + l15;
                bfr[ni] = *(const bf16x8*)(Bbuf + row * 128 + ((cs ^ (row & 7)) << 4));
            }
            #pragma unroll
            for (int mi = 0; mi < 2; ++mi)
            #pragma unroll
            for (int ni = 0; ni < 4; ++ni)
                acc[mi][ni] = __builtin_amdgcn_mfma_f32_16x16x32_bf16(af[mi], bfr[ni], acc[mi][ni], 0, 0, 0);
        }
        asm volatile("" ::: "memory");
        __builtin_amdgcn_s_barrier();
        if (t + 1 < nt) stageA((t + 1) * 64);
        if (t + 2 < nt) stageB(t & 1, (t + 2) * 64);
    }
    #pragma unroll
    for (int mi = 0; mi < 2; ++mi)
    #pragma unroll
    for (int ni = 0; ni < 4; ++ni)
    #pragma unroll
    for (int i = 0; i < 4; ++i) {
        int row = bm + wr * 32 + mi * 16 + g * 4 + i;
        int col = bn + wc * 64 + ni * 16 + l15;
        float v = acc[mi][ni][i];
        if constexpr (EPI == 1) v = fmaxf(v + bias[col], 0.f);
        ((u16*)Cout)[(long)row * N + col] = f2bf(v);
    }
}

// ---------------- 128x64 MFMA GEMM (narrow N) ----------------
// PIPE 0: single-buffer 24 KB (6 blk/CU) -- Wo (K=384), lm-head
// PIPE 1: A double + B single, 40 KB (4 blk/CU), counted vmcnt -- W2 (K=1536)
// EPI 2: +bias, +R -> f32; EPI 3: +bias, col<Nout -> f32 (stride Nout)
template<int EPI, int PIPE>
__global__ __launch_bounds__(256) void k_gemm_n64(
    const u16* __restrict__ A, const u16* __restrict__ Bt,
    const float* __restrict__ bias, const float* __restrict__ R,
    void* __restrict__ Cout, int M, int N, int K, int Nout)
{
    __shared__ __align__(16) u16 As[PIPE ? 2 : 1][128 * 64];
    __shared__ __align__(16) u16 Bs[64 * 64];
    const int bm = blockIdx.x * 128;
    const int bn = blockIdx.y * 64;
    const int tid = threadIdx.x;
    const int lane = tid & 63, w = tid >> 6;
    const int l15 = lane & 15, g = lane >> 4;
    const int lr = lane >> 3;
    const int lc = ((lane & 7) ^ lr) * 8;

    f32x4 acc[2][4] = {};
    const u16* Ag = A  + (long)(bm + w * 32 + lr) * K + lc;
    const u16* Bg = Bt + (long)(bn + w * 16 + lr) * K + lc;

    auto stageA = [&](int buf, int k0) {
        u16* Ad = As[buf] + (w * 4) * 512;
        #pragma unroll
        for (int s = 0; s < 4; ++s)
            gload16(Ag + (long)s * 8 * K + k0, Ad + s * 512);
    };
    auto stageB = [&](int k0) {
        u16* Bd = Bs + (w * 2) * 512;
        #pragma unroll
        for (int t = 0; t < 2; ++t)
            gload16(Bg + (long)t * 8 * K + k0, Bd + t * 512);
    };
    auto compute = [&](const char* Abuf) {
        const char* Bbuf = (const char*)Bs;
        #pragma unroll
        for (int hh = 0; hh < 2; ++hh) {
            const int cs = hh * 4 + g;
            bf16x8 af[2], bfr[4];
            #pragma unroll
            for (int mi = 0; mi < 2; ++mi) {
                int row = w * 32 + mi * 16 + l15;
                af[mi] = *(const bf16x8*)(Abuf + row * 128 + ((cs ^ (row & 7)) << 4));
            }
            #pragma unroll
            for (int ni = 0; ni < 4; ++ni) {
                int row = ni * 16 + l15;
                bfr[ni] = *(const bf16x8*)(Bbuf + row * 128 + ((cs ^ (row & 7)) << 4));
            }
            #pragma unroll
            for (int mi = 0; mi < 2; ++mi)
            #pragma unroll
            for (int ni = 0; ni < 4; ++ni)
                acc[mi][ni] = __builtin_amdgcn_mfma_f32_16x16x32_bf16(af[mi], bfr[ni], acc[mi][ni], 0, 0, 0);
        }
    };

    if constexpr (PIPE == 0) {
        for (int k0 = 0; k0 < K; k0 += 64) {
            stageA(0, k0);
            stageB(k0);
            __syncthreads();
            compute((const char*)As[0]);
            __syncthreads();
        }
    } else {
        const int nt = K / 64;
        stageA(0, 0);
        stageB(0);
        if (nt > 1) stageA(1, 64);
        for (int t = 0; t < nt; ++t) {
            if (t < nt - 1) asm volatile("s_waitcnt vmcnt(4)" ::: "memory");
            else            asm volatile("s_waitcnt vmcnt(0)" ::: "memory");
            __builtin_amdgcn_s_barrier();
            asm volatile("" ::: "memory");
            compute((const char*)As[t & 1]);
            asm volatile("" ::: "memory");
            __builtin_amdgcn_s_barrier();
            if (t + 1 < nt) stageB((t + 1) * 64);
            if (t + 2 < nt) stageA(t & 1, (t + 2) * 64);
        }
    }
    #pragma unroll
    for (int mi = 0; mi < 2; ++mi)
    #pragma unroll
    for (int ni = 0; ni < 4; ++ni)
    #pragma unroll
    for (int i = 0; i < 4; ++i) {
        int row = bm + w * 32 + mi * 16 + g * 4 + i;
        int col = bn + ni * 16 + l15;
        float v = acc[mi][ni][i];
        if constexpr (EPI == 2) {
            long o = (long)row * N + col;
            ((float*)Cout)[o] = v + bias[col] + R[o];
        } else {
            if (col < Nout)
                ((float*)Cout)[(long)row * Nout + col] = v + bias[col];
        }
    }
}

// ---------------- MFMA flash attention (validated; qkv stride CQ) ----------------
__global__ __launch_bounds__(256) void k_attn_mfma(const u16* __restrict__ qkv,
                                                   u16* __restrict__ att)
{
    __shared__ __align__(16) u16 ks[64][LDP];
    __shared__ __align__(16) u16 vt[64][LDP];
    __shared__ __align__(16) u16 pt[4][16][LDP];
    const int qt = blockIdx.x, hh = blockIdx.y, b = blockIdx.z;
    const int tid = threadIdx.x, lane = tid & 63, w = tid >> 6;
    const int l15 = lane & 15, g = lane >> 4;
    const int q0 = qt * 64;
    const long tokbase = (long)b * Tt;
    const float scale = 0.051031036307982884f;

    bf16x8 qa0, qa1;
    {
        const u16* qp = qkv + (tokbase + q0 + w * 16 + l15) * CQ + hh * HD + g * 8;
        qa0 = *(const bf16x8*)(qp);
        qa1 = *(const bf16x8*)(qp + 32);
    }
    f32x4 o[4] = {};
    float mrow[4] = {-1e30f, -1e30f, -1e30f, -1e30f};
    float lrow[4] = {0.f, 0.f, 0.f, 0.f};

    for (int kt = 0; kt <= qt; ++kt) {
        {
            int key = tid >> 2, c0 = (tid & 3) * 16;
            const u16* kg = qkv + (tokbase + kt * 64 + key) * CQ + Cc     + hh * HD + c0;
            const u16* vg = qkv + (tokbase + kt * 64 + key) * CQ + 2 * Cc + hh * HD + c0;
            *(bf16x8*)&ks[key][c0]     = *(const bf16x8*)kg;
            *(bf16x8*)&ks[key][c0 + 8] = *(const bf16x8*)(kg + 8);
            bf16x8 v0 = *(const bf16x8*)vg;
            bf16x8 v1 = *(const bf16x8*)(vg + 8);
            #pragma unroll
            for (int j = 0; j < 8; ++j) vt[c0 + j][key]     = (u16)v0[j];
            #pragma unroll
            for (int j = 0; j < 8; ++j) vt[c0 + 8 + j][key] = (u16)v1[j];
        }
        __syncthreads();
        f32x4 s[4] = {};
        #pragma unroll
        for (int c = 0; c < 4; ++c) {
            bf16x8 kb0 = *(const bf16x8*)&ks[c * 16 + l15][g * 8];
            bf16x8 kb1 = *(const bf16x8*)&ks[c * 16 + l15][32 + g * 8];
            s[c] = __builtin_amdgcn_mfma_f32_16x16x32_bf16(qa0, kb0, s[c], 0, 0, 0);
            s[c] = __builtin_amdgcn_mfma_f32_16x16x32_bf16(qa1, kb1, s[c], 0, 0, 0);
        }
        const bool diag = (kt == qt);
        #pragma unroll
        for (int c = 0; c < 4; ++c)
        #pragma unroll
        for (int i = 0; i < 4; ++i) {
            float v = s[c][i] * scale;
            if (diag && (c * 16 + l15 > w * 16 + 4 * g + i)) v = -1e30f;
            s[c][i] = v;
        }
        #pragma unroll
        for (int i = 0; i < 4; ++i) {
            float m0 = fmaxf(fmaxf(s[0][i], s[1][i]), fmaxf(s[2][i], s[3][i]));
            #pragma unroll
            for (int mm = 1; mm < 16; mm <<= 1) m0 = fmaxf(m0, __shfl_xor(m0, mm, 64));
            float mn = fmaxf(mrow[i], m0);
            float alpha = __expf(mrow[i] - mn);
            mrow[i] = mn;
            float sum = 0.f;
            #pragma unroll
            for (int c = 0; c < 4; ++c) {
                float p = __expf(s[c][i] - mn);
                s[c][i] = p;
                sum += p;
            }
            #pragma unroll
            for (int mm = 1; mm < 16; mm <<= 1) sum += __shfl_xor(sum, mm, 64);
            lrow[i] = lrow[i] * alpha + sum;
            #pragma unroll
            for (int d = 0; d < 4; ++d) o[d][i] *= alpha;
        }
        #pragma unroll
        for (int c = 0; c < 4; ++c)
        #pragma unroll
        for (int i = 0; i < 4; ++i)
            pt[w][g * 4 + i][c * 16 + l15] = f2bf(s[c][i]);
        bf16x8 pa0 = *(const bf16x8*)&pt[w][l15][g * 8];
        bf16x8 pa1 = *(const bf16x8*)&pt[w][l15][32 + g * 8];
        #pragma unroll
        for (int d = 0; d < 4; ++d) {
            bf16x8 vb0 = *(const bf16x8*)&vt[d * 16 + l15][g * 8];
            bf16x8 vb1 = *(const bf16x8*)&vt[d * 16 + l15][32 + g * 8];
            o[d] = __builtin_amdgcn_mfma_f32_16x16x32_bf16(pa0, vb0, o[d], 0, 0, 0);
            o[d] = __builtin_amdgcn_mfma_f32_16x16x32_bf16(pa1, vb1, o[d], 0, 0, 0);
        }
        __syncthreads();
    }
    #pragma unroll
    for (int i = 0; i < 4; ++i) {
        float inv = 1.f / lrow[i];
        int row = q0 + w * 16 + g * 4 + i;
        u16* ap = att + (tokbase + row) * Cc + hh * HD;
        #pragma unroll
        for (int d = 0; d < 4; ++d)
            ap[d * 16 + l15] = f2bf(o[d][i] * inv);
    }
}

extern "C" void kernel_launch(void* const* d_in, const int* in_sizes, int n_in,
                              void* d_out, int out_size, void* d_ws, size_t ws_size,
                              hipStream_t stream)
{
    (void)in_sizes; (void)n_in; (void)out_size; (void)ws_size;
    const int*   idx  = (const int*)d_in[0];
    const float* tok  = (const float*)d_in[1];
    const float* pos  = (const float*)d_in[2];
    const float* Wq   = (const float*)d_in[3];
    const float* Wk   = (const float*)d_in[4];
    const float* Wv   = (const float*)d_in[5];
    const float* Wo   = (const float*)d_in[6];
    const float* bo   = (const float*)d_in[7];
    const float* ln1g = (const float*)d_in[8];
    const float* ln1b = (const float*)d_in[9];
    const float* ln2g = (const float*)d_in[10];
    const float* ln2b = (const float*)d_in[11];
    const float* W1   = (const float*)d_in[12];
    const float* b1   = (const float*)d_in[13];
    const float* W2   = (const float*)d_in[14];
    const float* b2   = (const float*)d_in[15];
    const float* lnfg = (const float*)d_in[16];
    const float* lnfb = (const float*)d_in[17];
    const float* Wlm  = (const float*)d_in[18];
    const float* blm  = (const float*)d_in[19];

    char* w = (char*)d_ws;
    auto carve = [&](size_t bytes) { char* p = w; w += (bytes + 255) & ~(size_t)255; return p; };
    float* x   = (float*)carve((size_t)NT * Cc * 4);
    u16*  big  = (u16*)carve((size_t)NT * FF * 2);   // fb (NT*FF) and qkvb (NT*CQ) share
    u16*  h    = (u16*)carve((size_t)NT * Cc * 2);
    u16*  ab   = (u16*)carve((size_t)NT * Cc * 2);
    u16*  Wqkvt= (u16*)carve((size_t)Ll * CQ * Cc * 2);
    u16*  Wot  = (u16*)carve((size_t)Ll * Cc * Cc * 2);
    u16*  W1t  = (u16*)carve((size_t)Ll * FF * Cc * 2);
    u16*  W2t  = (u16*)carve((size_t)Ll * Cc * FF * 2);
    u16*  Wlmt = (u16*)carve((size_t)128 * Cc * 2);
    u16*  qkvb = big;
    u16*  fb   = big;

    const int TPB = 256;
    k_cvtT_all<<<5184, TPB, 0, stream>>>(Wq, Wk, Wv, Wo, W1, W2, Wqkvt, Wot, W1t, W2t);
    k_cvtT_lm<<<(128 * Cc + 255) / 256, TPB, 0, stream>>>(Wlm, Wlmt);
    k_embed_ln<<<NT / 4, TPB, 0, stream>>>(idx, tok, pos, ln1g, ln1b, x, h);

    for (int l = 0; l < Ll; ++l) {
        if (l > 0)
            k_ln<<<NT / 4, TPB, 0, stream>>>(x, ln1g + l * Cc, ln1b + l * Cc, h);
        k_gemm128<0><<<dim3(NT / 128, CQ / 128), 512, 0, stream>>>(
            h, Wqkvt + (size_t)l * CQ * Cc, nullptr, qkvb, NT, CQ, Cc);
        k_attn_mfma<<<dim3(4, Hh, Bb), TPB, 0, stream>>>(qkvb, ab);
        k_gemm_n64<2, 0><<<dim3(NT / 128, Cc / 64), TPB, 0, stream>>>(
            ab, Wot + (size_t)l * Cc * Cc, bo + l * Cc, x, x, NT, Cc, Cc, Cc);
        k_ln<<<NT / 4, TPB, 0, stream>>>(x, ln2g + l * Cc, ln2b + l * Cc, h);
        k_gemm128<1><<<dim3(NT / 128, FF / 128), 512, 0, stream>>>(
            h, W1t + (size_t)l * FF * Cc, b1 + l * FF, fb, NT, FF, Cc);
        k_gemm_n64<2, 1><<<dim3(NT / 128, Cc / 64), TPB, 0, stream>>>(
            fb, W2t + (size_t)l * Cc * FF, b2 + l * Cc, x, x, NT, Cc, FF, Cc);
    }
    k_ln<<<NT / 4, TPB, 0, stream>>>(x, lnfg, lnfb, h);
    k_gemm_n64<3, 0><<<dim3(NT / 128, 2), TPB, 0, stream>>>(
        h, Wlmt, blm, nullptr, (float*)d_out, NT, 128, Cc, Vv);
}

// Round 25
// 426.359 us; speedup vs baseline: 1.0120x; 1.0016x over previous
//
#include <hip/hip_runtime.h>

#define Bb 64
#define Tt 256
#define Cc 384
#define Ll 3
#define Hh 6
#define HD 64
#define Vv 65
#define FF 1536
#define NT (Bb*Tt)        // 16384 tokens
#define CQ 1152           // fused qkv width
#define LDP 72            // attn LDS row stride (u16)

typedef unsigned short u16;
typedef unsigned int   u32;
typedef __attribute__((ext_vector_type(8))) short bf16x8;
typedef __attribute__((ext_vector_type(4))) float f32x4;

__device__ __forceinline__ float bf2f(u16 u) {
    u32 v = ((u32)u) << 16; float f; __builtin_memcpy(&f, &v, 4); return f;
}
__device__ __forceinline__ u16 f2bf(float f) {
    u32 u; __builtin_memcpy(&u, &f, 4);
    u = (u + 0x7fffu + ((u >> 16) & 1u)) >> 16;
    return (u16)u;
}
__device__ __forceinline__ void gload16(const void* g, void* l) {
    __builtin_amdgcn_global_load_lds(
        (const __attribute__((address_space(1))) u32*)g,
        (__attribute__((address_space(3))) u32*)l, 16, 0, 0);
}

// ---------------- fused embed + LN(layer0): one wave per token, float2-vectorized ----------------
__global__ __launch_bounds__(256) void k_embed_ln(const int* __restrict__ idx,
    const float* __restrict__ tok, const float* __restrict__ pos,
    const float* __restrict__ g, const float* __restrict__ b,
    float* __restrict__ x, u16* __restrict__ h)
{
    int bt   = (int)((blockIdx.x * 256 + threadIdx.x) >> 6);
    int lane = threadIdx.x & 63;
    int t = bt % Tt;
    const float2* tr = (const float2*)(tok + (long)idx[bt] * Cc);
    const float2* pr = (const float2*)(pos + (long)t * Cc);
    float2 v[3]; float s = 0.f;
    #pragma unroll
    for (int j = 0; j < 3; ++j) {
        int c = lane + 64 * j;
        float2 tv = tr[c], pv = pr[c];
        v[j].x = tv.x + pv.x; v[j].y = tv.y + pv.y;
        s += v[j].x + v[j].y;
    }
    float2* xr = (float2*)(x + (long)bt * Cc);
    #pragma unroll
    for (int j = 0; j < 3; ++j) xr[lane + 64 * j] = v[j];
    #pragma unroll
    for (int m = 32; m; m >>= 1) s += __shfl_xor(s, m, 64);
    float mean = s * (1.f / 384.f);
    float q = 0.f;
    #pragma unroll
    for (int j = 0; j < 3; ++j) {
        float dx = v[j].x - mean, dy = v[j].y - mean;
        q += dx * dx + dy * dy;
    }
    #pragma unroll
    for (int m = 32; m; m >>= 1) q += __shfl_xor(q, m, 64);
    float rstd = rsqrtf(q * (1.f / 384.f) + 1e-5f);
    u32* hr = (u32*)(h + (long)bt * Cc);
    const float2* gr = (const float2*)g;
    const float2* br = (const float2*)b;
    #pragma unroll
    for (int j = 0; j < 3; ++j) {
        int c = lane + 64 * j;
        float2 gv = gr[c], bv = br[c];
        u32 lo = f2bf((v[j].x - mean) * rstd * gv.x + bv.x);
        u32 hi = f2bf((v[j].y - mean) * rstd * gv.y + bv.y);
        hr[c] = lo | (hi << 16);
    }
}

// ---------------- layernorm: fp32 in -> bf16 out, one wave per row, float2-vectorized ----------------
__global__ __launch_bounds__(256) void k_ln(const float* __restrict__ x,
    const float* __restrict__ g, const float* __restrict__ b, u16* __restrict__ h)
{
    int row  = (int)((blockIdx.x * 256 + threadIdx.x) >> 6);
    int lane = threadIdx.x & 63;
    const float2* xr = (const float2*)(x + (long)row * Cc);
    float2 v[3]; float s = 0.f;
    #pragma unroll
    for (int j = 0; j < 3; ++j) { v[j] = xr[lane + 64 * j]; s += v[j].x + v[j].y; }
    #pragma unroll
    for (int m = 32; m; m >>= 1) s += __shfl_xor(s, m, 64);
    float mean = s * (1.f / 384.f);
    float q = 0.f;
    #pragma unroll
    for (int j = 0; j < 3; ++j) {
        float dx = v[j].x - mean, dy = v[j].y - mean;
        q += dx * dx + dy * dy;
    }
    #pragma unroll
    for (int m = 32; m; m >>= 1) q += __shfl_xor(q, m, 64);
    float rstd = rsqrtf(q * (1.f / 384.f) + 1e-5f);
    u32* hr = (u32*)(h + (long)row * Cc);
    const float2* gr = (const float2*)g;
    const float2* br = (const float2*)b;
    #pragma unroll
    for (int j = 0; j < 3; ++j) {
        int c = lane + 64 * j;
        float2 gv = gr[c], bv = br[c];
        u32 lo = f2bf((v[j].x - mean) * rstd * gv.x + bv.x);
        u32 hi = f2bf((v[j].y - mean) * rstd * gv.y + bv.y);
        hr[c] = lo | (hi << 16);
    }
}

// ---------------- fused weight convert+transpose (all 18 big matrices) ----------------
__global__ __launch_bounds__(256) void k_cvtT_all(
    const float* __restrict__ Wq, const float* __restrict__ Wk,
    const float* __restrict__ Wv, const float* __restrict__ Wo,
    const float* __restrict__ W1, const float* __restrict__ W2,
    u16* __restrict__ Wqkvt, u16* __restrict__ Wot,
    u16* __restrict__ W1t, u16* __restrict__ W2t)
{
    int t = blockIdx.x;
    const float* src; u16* dst; int K, N, tt;
    if (t < 1728) {
        int m = t / 144; tt = t % 144; K = Cc; N = Cc;
        if (m < 9) {
            int l = m / 3, q = m % 3;
            src = (q == 0 ? Wq : q == 1 ? Wk : Wv) + (size_t)l * Cc * Cc;
            dst = Wqkvt + (size_t)l * CQ * Cc + (size_t)q * Cc * Cc;
        } else {
            int l = m - 9;
            src = Wo + (size_t)l * Cc * Cc;
            dst = Wot + (size_t)l * Cc * Cc;
        }
    } else if (t < 3456) {
        int u = t - 1728; int l = u / 576; tt = u % 576; K = Cc; N = FF;
        src = W1 + (size_t)l * Cc * FF; dst = W1t + (size_t)l * FF * Cc;
    } else {
        int u = t - 3456; int l = u / 576; tt = u % 576; K = FF; N = Cc;
        src = W2 + (size_t)l * FF * Cc; dst = W2t + (size_t)l * Cc * FF;
    }
    int nk = K / 32;
    int kt = (tt % nk) * 32, nt = (tt / nk) * 32;
    __shared__ u16 tile[32][33];
    int tx = threadIdx.x & 31, ty = threadIdx.x >> 5;
    #pragma unroll
    for (int r = 0; r < 4; ++r)
        tile[ty + 8 * r][tx] = f2bf(src[(long)(kt + ty + 8 * r) * N + nt + tx]);
    __syncthreads();
    #pragma unroll
    for (int r = 0; r < 4; ++r)
        dst[(long)(nt + ty + 8 * r) * K + kt + tx] = tile[tx][ty + 8 * r];
}

// Wlm: [384][65] f32 -> padded [128][384] bf16
__global__ void k_cvtT_lm(const float* __restrict__ W, u16* __restrict__ Wt)
{
    int i = blockIdx.x * 256 + threadIdx.x;
    if (i >= 128 * Cc) return;
    int k = i % Cc, n = i / Cc;
    Wt[i] = (n < Vv) ? f2bf(W[(long)k * Vv + n]) : (u16)0;
}

// ---------------- 128x128 MFMA GEMM, 512 threads (8 waves), A single + B double (r24) ----------------
// EPI 0: ->bf16 (no bias); EPI 1: +bias, relu -> bf16
template<int EPI>
__global__ __launch_bounds__(512, 6) void k_gemm128(
    const u16* __restrict__ A, const u16* __restrict__ Bt,
    const float* __restrict__ bias, void* __restrict__ Cout, int M, int N, int K)
{
    __shared__ __align__(16) u16 As[128 * 64];      // 16 KB (single)
    __shared__ __align__(16) u16 Bs[2][128 * 64];   // 32 KB (double)
    const int bm = blockIdx.x * 128;
    const int bn = blockIdx.y * 128;
    const int tid = threadIdx.x;
    const int lane = tid & 63, w = tid >> 6;       // w = 0..7
    const int wr = w >> 1, wc = w & 1;             // wave tile: rows wr*32, cols wc*64
    const int l15 = lane & 15, g = lane >> 4;
    const int lr = lane >> 3;
    const int lc = ((lane & 7) ^ lr) * 8;          // pre-swizzled source column

    f32x4 acc[2][4] = {};
    const u16* Ag = A  + (long)(bm + w * 16 + lr) * K + lc;
    const u16* Bg = Bt + (long)(bn + w * 16 + lr) * K + lc;

    auto stageA = [&](int k0) {
        u16* Ad = As + (w * 2) * 512;
        #pragma unroll
        for (int s = 0; s < 2; ++s)
            gload16(Ag + (long)s * 8 * K + k0, Ad + s * 512);
    };
    auto stageB = [&](int buf, int k0) {
        u16* Bd = Bs[buf] + (w * 2) * 512;
        #pragma unroll
        for (int s = 0; s < 2; ++s)
            gload16(Bg + (long)s * 8 * K + k0, Bd + s * 512);
    };
    const int nt = K / 64;
    stageB(0, 0);
    stageA(0);
    if (nt > 1) stageB(1, 64);
    for (int t = 0; t < nt; ++t) {
        if (t < nt - 1) asm volatile("s_waitcnt vmcnt(2)" ::: "memory");
        else            asm volatile("s_waitcnt vmcnt(0)" ::: "memory");
        __builtin_amdgcn_s_barrier();
        asm volatile("" ::: "memory");
        const char* Abuf = (const char*)As;
        const char* Bbuf = (const char*)Bs[t & 1];
        #pragma unroll
        for (int hh = 0; hh < 2; ++hh) {
            const int cs = hh * 4 + g;
            bf16x8 af[2], bfr[4];
            #pragma unroll
            for (int mi = 0; mi < 2; ++mi) {
                int row = wr * 32 + mi * 16 + l15;
                af[mi] = *(const bf16x8*)(Abuf + row * 128 + ((cs ^ (row & 7)) << 4));
            }
            #pragma unroll
            for (int ni = 0; ni < 4; ++ni) {
                int row = wc * 64 + ni * 16 + l15;
                bfr[ni] = *(const bf16x8*)(Bbuf + row * 128 + ((cs ^ (row & 7)) << 4));
            }
            #pragma unroll
            for (int mi = 0; mi < 2; ++mi)
            #pragma unroll
            for (int ni = 0; ni < 4; ++ni)
                acc[mi][ni] = __builtin_amdgcn_mfma_f32_16x16x32_bf16(af[mi], bfr[ni], acc[mi][ni], 0, 0, 0);
        }
        asm volatile("" ::: "memory");
        __builtin_amdgcn_s_barrier();
        if (t + 1 < nt) stageA((t + 1) * 64);
        if (t + 2 < nt) stageB(t & 1, (t + 2) * 64);
    }
    #pragma unroll
    for (int mi = 0; mi < 2; ++mi)
    #pragma unroll
    for (int ni = 0; ni < 4; ++ni)
    #pragma unroll
    for (int i = 0; i < 4; ++i) {
        int row = bm + wr * 32 + mi * 16 + g * 4 + i;
        int col = bn + wc * 64 + ni * 16 + l15;
        float v = acc[mi][ni][i];
        if constexpr (EPI == 1) v = fmaxf(v + bias[col], 0.f);
        ((u16*)Cout)[(long)row * N + col] = f2bf(v);
    }
}

// ---------------- 128x64 MFMA GEMM (narrow N), 512 threads (8 waves), wave tile 32x32 ----------------
// PIPE 0: single-buffer 24 KB -- Wo (K=384), lm-head
// PIPE 1: A double + B single, 40 KB, counted vmcnt(2) -- W2 (K=1536)
// Staging: A 2 segments/wave, B 1 segment/wave (all gload_lds, order-stable).
// EPI 2: +bias, +R -> f32; EPI 3: +bias, col<Nout -> f32 (stride Nout)
template<int EPI, int PIPE>
__global__ __launch_bounds__(512, 6) void k_gemm_n64(
    const u16* __restrict__ A, const u16* __restrict__ Bt,
    const float* __restrict__ bias, const float* __restrict__ R,
    void* __restrict__ Cout, int M, int N, int K, int Nout)
{
    __shared__ __align__(16) u16 As[PIPE ? 2 : 1][128 * 64];
    __shared__ __align__(16) u16 Bs[64 * 64];
    const int bm = blockIdx.x * 128;
    const int bn = blockIdx.y * 64;
    const int tid = threadIdx.x;
    const int lane = tid & 63, w = tid >> 6;       // w = 0..7
    const int wr = w >> 1, wc = w & 1;             // wave tile: rows wr*32, cols wc*32
    const int l15 = lane & 15, g = lane >> 4;
    const int lr = lane >> 3;
    const int lc = ((lane & 7) ^ lr) * 8;

    f32x4 acc[2][2] = {};
    const u16* Ag = A  + (long)(bm + w * 16 + lr) * K + lc;   // A segs 2w, 2w+1
    const u16* Bg = Bt + (long)(bn + w * 8  + lr) * K + lc;   // B seg w

    auto stageA = [&](int buf, int k0) {
        u16* Ad = As[buf] + (w * 2) * 512;
        #pragma unroll
        for (int s = 0; s < 2; ++s)
            gload16(Ag + (long)s * 8 * K + k0, Ad + s * 512);
    };
    auto stageB = [&](int k0) {
        u16* Bd = Bs + w * 512;
        gload16(Bg + k0, Bd);
    };
    auto compute = [&](const char* Abuf) {
        const char* Bbuf = (const char*)Bs;
        #pragma unroll
        for (int hh = 0; hh < 2; ++hh) {
            const int cs = hh * 4 + g;
            bf16x8 af[2], bfr[2];
            #pragma unroll
            for (int mi = 0; mi < 2; ++mi) {
                int row = wr * 32 + mi * 16 + l15;
                af[mi] = *(const bf16x8*)(Abuf + row * 128 + ((cs ^ (row & 7)) << 4));
            }
            #pragma unroll
            for (int ni = 0; ni < 2; ++ni) {
                int row = wc * 32 + ni * 16 + l15;
                bfr[ni] = *(const bf16x8*)(Bbuf + row * 128 + ((cs ^ (row & 7)) << 4));
            }
            #pragma unroll
            for (int mi = 0; mi < 2; ++mi)
            #pragma unroll
            for (int ni = 0; ni < 2; ++ni)
                acc[mi][ni] = __builtin_amdgcn_mfma_f32_16x16x32_bf16(af[mi], bfr[ni], acc[mi][ni], 0, 0, 0);
        }
    };

    if constexpr (PIPE == 0) {
        for (int k0 = 0; k0 < K; k0 += 64) {
            stageA(0, k0);
            stageB(k0);
            __syncthreads();
            compute((const char*)As[0]);
            __syncthreads();
        }
    } else {
        const int nt = K / 64;
        stageA(0, 0);
        stageB(0);
        if (nt > 1) stageA(1, 64);
        for (int t = 0; t < nt; ++t) {
            if (t < nt - 1) asm volatile("s_waitcnt vmcnt(2)" ::: "memory");
            else            asm volatile("s_waitcnt vmcnt(0)" ::: "memory");
            __builtin_amdgcn_s_barrier();
            asm volatile("" ::: "memory");
            compute((const char*)As[t & 1]);
            asm volatile("" ::: "memory");
            __builtin_amdgcn_s_barrier();
            if (t + 1 < nt) stageB((t + 1) * 64);
            if (t + 2 < nt) stageA(t & 1, (t + 2) * 64);
        }
    }
    #pragma unroll
    for (int mi = 0; mi < 2; ++mi)
    #pragma unroll
    for (int ni = 0; ni < 2; ++ni)
    #pragma unroll
    for (int i = 0; i < 4; ++i) {
        int row = bm + wr * 32 + mi * 16 + g * 4 + i;
        int col = bn + wc * 32 + ni * 16 + l15;
        float v = acc[mi][ni][i];
        if constexpr (EPI == 2) {
            long o = (long)row * N + col;
            ((float*)Cout)[o] = v + bias[col] + R[o];
        } else {
            if (col < Nout)
                ((float*)Cout)[(long)row * Nout + col] = v + bias[col];
        }
    }
}

// ---------------- MFMA flash attention (validated; qkv stride CQ) ----------------
__global__ __launch_bounds__(256) void k_attn_mfma(const u16* __restrict__ qkv,
                                                   u16* __restrict__ att)
{
    __shared__ __align__(16) u16 ks[64][LDP];
    __shared__ __align__(16) u16 vt[64][LDP];
    __shared__ __align__(16) u16 pt[4][16][LDP];
    const int qt = blockIdx.x, hh = blockIdx.y, b = blockIdx.z;
    const int tid = threadIdx.x, lane = tid & 63, w = tid >> 6;
    const int l15 = lane & 15, g = lane >> 4;
    const int q0 = qt * 64;
    const long tokbase = (long)b * Tt;
    const float scale = 0.051031036307982884f;

    bf16x8 qa0, qa1;
    {
        const u16* qp = qkv + (tokbase + q0 + w * 16 + l15) * CQ + hh * HD + g * 8;
        qa0 = *(const bf16x8*)(qp);
        qa1 = *(const bf16x8*)(qp + 32);
    }
    f32x4 o[4] = {};
    float mrow[4] = {-1e30f, -1e30f, -1e30f, -1e30f};
    float lrow[4] = {0.f, 0.f, 0.f, 0.f};

    for (int kt = 0; kt <= qt; ++kt) {
        {
            int key = tid >> 2, c0 = (tid & 3) * 16;
            const u16* kg = qkv + (tokbase + kt * 64 + key) * CQ + Cc     + hh * HD + c0;
            const u16* vg = qkv + (tokbase + kt * 64 + key) * CQ + 2 * Cc + hh * HD + c0;
            *(bf16x8*)&ks[key][c0]     = *(const bf16x8*)kg;
            *(bf16x8*)&ks[key][c0 + 8] = *(const bf16x8*)(kg + 8);
            bf16x8 v0 = *(const bf16x8*)vg;
            bf16x8 v1 = *(const bf16x8*)(vg + 8);
            #pragma unroll
            for (int j = 0; j < 8; ++j) vt[c0 + j][key]     = (u16)v0[j];
            #pragma unroll
            for (int j = 0; j < 8; ++j) vt[c0 + 8 + j][key] = (u16)v1[j];
        }
        __syncthreads();
        f32x4 s[4] = {};
        #pragma unroll
        for (int c = 0; c < 4; ++c) {
            bf16x8 kb0 = *(const bf16x8*)&ks[c * 16 + l15][g * 8];
            bf16x8 kb1 = *(const bf16x8*)&ks[c * 16 + l15][32 + g * 8];
            s[c] = __builtin_amdgcn_mfma_f32_16x16x32_bf16(qa0, kb0, s[c], 0, 0, 0);
            s[c] = __builtin_amdgcn_mfma_f32_16x16x32_bf16(qa1, kb1, s[c], 0, 0, 0);
        }
        const bool diag = (kt == qt);
        #pragma unroll
        for (int c = 0; c < 4; ++c)
        #pragma unroll
        for (int i = 0; i < 4; ++i) {
            float v = s[c][i] * scale;
            if (diag && (c * 16 + l15 > w * 16 + 4 * g + i)) v = -1e30f;
            s[c][i] = v;
        }
        #pragma unroll
        for (int i = 0; i < 4; ++i) {
            float m0 = fmaxf(fmaxf(s[0][i], s[1][i]), fmaxf(s[2][i], s[3][i]));
            #pragma unroll
            for (int mm = 1; mm < 16; mm <<= 1) m0 = fmaxf(m0, __shfl_xor(m0, mm, 64));
            float mn = fmaxf(mrow[i], m0);
            float alpha = __expf(mrow[i] - mn);
            mrow[i] = mn;
            float sum = 0.f;
            #pragma unroll
            for (int c = 0; c < 4; ++c) {
                float p = __expf(s[c][i] - mn);
                s[c][i] = p;
                sum += p;
            }
            #pragma unroll
            for (int mm = 1; mm < 16; mm <<= 1) sum += __shfl_xor(sum, mm, 64);
            lrow[i] = lrow[i] * alpha + sum;
            #pragma unroll
            for (int d = 0; d < 4; ++d) o[d][i] *= alpha;
        }
        #pragma unroll
        for (int c = 0; c < 4; ++c)
        #pragma unroll
        for (int i = 0; i < 4; ++i)
            pt[w][g * 4 + i][c * 16 + l15] = f2bf(s[c][i]);
        bf16x8 pa0 = *(const bf16x8*)&pt[w][l15][g * 8];
        bf16x8 pa1 = *(const bf16x8*)&pt[w][l15][32 + g * 8];
        #pragma unroll
        for (int d = 0; d < 4; ++d) {
            bf16x8 vb0 = *(const bf16x8*)&vt[d * 16 + l15][g * 8];
            bf16x8 vb1 = *(const bf16x8*)&vt[d * 16 + l15][32 + g * 8];
            o[d] = __builtin_amdgcn_mfma_f32_16x16x32_bf16(pa0, vb0, o[d], 0, 0, 0);
            o[d] = __builtin_amdgcn_mfma_f32_16x16x32_bf16(pa1, vb1, o[d], 0, 0, 0);
        }
        __syncthreads();
    }
    #pragma unroll
    for (int i = 0; i < 4; ++i) {
        float inv = 1.f / lrow[i];
        int row = q0 + w * 16 + g * 4 + i;
        u16* ap = att + (tokbase + row) * Cc + hh * HD;
        #pragma unroll
        for (int d = 0; d < 4; ++d)
            ap[d * 16 + l15] = f2bf(o[d][i] * inv);
    }
}

extern "C" void kernel_launch(void* const* d_in, const int* in_sizes, int n_in,
                              void* d_out, int out_size, void* d_ws, size_t ws_size,
                              hipStream_t stream)
{
    (void)in_sizes; (void)n_in; (void)out_size; (void)ws_size;
    const int*   idx  = (const int*)d_in[0];
    const float* tok  = (const float*)d_in[1];
    const float* pos  = (const float*)d_in[2];
    const float* Wq   = (const float*)d_in[3];
    const float* Wk   = (const float*)d_in[4];
    const float* Wv   = (const float*)d_in[5];
    const float* Wo   = (const float*)d_in[6];
    const float* bo   = (const float*)d_in[7];
    const float* ln1g = (const float*)d_in[8];
    const float* ln1b = (const float*)d_in[9];
    const float* ln2g = (const float*)d_in[10];
    const float* ln2b = (const float*)d_in[11];
    const float* W1   = (const float*)d_in[12];
    const float* b1   = (const float*)d_in[13];
    const float* W2   = (const float*)d_in[14];
    const float* b2   = (const float*)d_in[15];
    const float* lnfg = (const float*)d_in[16];
    const float* lnfb = (const float*)d_in[17];
    const float* Wlm  = (const float*)d_in[18];
    const float* blm  = (const float*)d_in[19];

    char* w = (char*)d_ws;
    auto carve = [&](size_t bytes) { char* p = w; w += (bytes + 255) & ~(size_t)255; return p; };
    float* x   = (float*)carve((size_t)NT * Cc * 4);
    u16*  big  = (u16*)carve((size_t)NT * FF * 2);   // fb (NT*FF) and qkvb (NT*CQ) share
    u16*  h    = (u16*)carve((size_t)NT * Cc * 2);
    u16*  ab   = (u16*)carve((size_t)NT * Cc * 2);
    u16*  Wqkvt= (u16*)carve((size_t)Ll * CQ * Cc * 2);
    u16*  Wot  = (u16*)carve((size_t)Ll * Cc * Cc * 2);
    u16*  W1t  = (u16*)carve((size_t)Ll * FF * Cc * 2);
    u16*  W2t  = (u16*)carve((size_t)Ll * Cc * FF * 2);
    u16*  Wlmt = (u16*)carve((size_t)128 * Cc * 2);
    u16*  qkvb = big;
    u16*  fb   = big;

    const int TPB = 256;
    k_cvtT_all<<<5184, TPB, 0, stream>>>(Wq, Wk, Wv, Wo, W1, W2, Wqkvt, Wot, W1t, W2t);
    k_cvtT_lm<<<(128 * Cc + 255) / 256, TPB, 0, stream>>>(Wlm, Wlmt);
    k_embed_ln<<<NT / 4, TPB, 0, stream>>>(idx, tok, pos, ln1g, ln1b, x, h);

    for (int l = 0; l < Ll; ++l) {
        if (l > 0)
            k_ln<<<NT / 4, TPB, 0, stream>>>(x, ln1g + l * Cc, ln1b + l * Cc, h);
        k_gemm128<0><<<dim3(NT / 128, CQ / 128), 512, 0, stream>>>(
            h, Wqkvt + (size_t)l * CQ * Cc, nullptr, qkvb, NT, CQ, Cc);
        k_attn_mfma<<<dim3(4, Hh, Bb), TPB, 0, stream>>>(qkvb, ab);
        k_gemm_n64<2, 0><<<dim3(NT / 128, Cc / 64), 512, 0, stream>>>(
            ab, Wot + (size_t)l * Cc * Cc, bo + l * Cc, x, x, NT, Cc, Cc, Cc);
        k_ln<<<NT / 4, TPB, 0, stream>>>(x, ln2g + l * Cc, ln2b + l * Cc, h);
        k_gemm128<1><<<dim3(NT / 128, FF / 128), 512, 0, stream>>>(
            h, W1t + (size_t)l * FF * Cc, b1 + l * FF, fb, NT, FF, Cc);
        k_gemm_n64<2, 1><<<dim3(NT / 128, Cc / 64), 512, 0, stream>>>(
            fb, W2t + (size_t)l * Cc * FF, b2 + l * Cc, x, x, NT, Cc, FF, Cc);
    }
    k_ln<<<NT / 4, TPB, 0, stream>>>(x, lnfg, lnfb, h);
    k_gemm_n64<3, 0><<<dim3(NT / 128, 2), 512, 0, stream>>>(
        h, Wlmt, blm, nullptr, (float*)d_out, NT, 128, Cc, Vv);
}